// Round 1
// baseline (136.429 us; speedup 1.0000x reference)
//
#include <hip/hip_runtime.h>

// WaveletKANLinear: out[b,o] = sum_i silu(x[b,i])*BW[o,i]
//                            + sum_i ((xs^2-1)*exp(-xs^2/2))*WW[o,i] + bias[o]
//   xs = (x[b,i]-T[o,i])/S[o,i]
//
// Refactored inner triple (5 VALU + 1 exp2), with per-(o,i) precompute at
// staging: a2 = C2/s^2, m1 = -2*a2*t, m2 = a2*t^2, w2 = w/C2, C2 = -0.5*log2(e)
//   u = a2*(x-t)^2 = x*(x*a2 + m1) + m2         (2 fma)
//   e = exp2(u)                                  (1 trans)
//   g = (t2-1)*w = u*w2 - w                      (1 fma, -w via modifier)
//   accW += g*e ; accB += sx*bb                  (2 fma)

constexpr int IN_F  = 512;
constexpr int OUT_F = 512;
constexpr int BATCH = 1024;
constexpr int BT    = 32;   // batch tile per block
constexpr int OT    = 32;   // out tile per block
constexpr int IT    = 64;   // k chunk
constexpr int PITCH = IT + 4;  // +4 floats keeps 16B align, breaks bank stride

#define LOG2E      1.44269504088896f
#define C2         (-0.72134752044448f)   /* -0.5*log2(e) */
#define RC2        (-1.38629436111989f)   /* 1/C2 = -2*ln2 */

__device__ __forceinline__ float fast_exp2(float v) {
#if __has_builtin(__builtin_amdgcn_exp2f)
  return __builtin_amdgcn_exp2f(v);
#else
  return exp2f(v);
#endif
}
__device__ __forceinline__ float fast_rcp(float v) {
#if __has_builtin(__builtin_amdgcn_rcpf)
  return __builtin_amdgcn_rcpf(v);
#else
  return 1.0f / v;
#endif
}

__global__ __launch_bounds__(256, 2)
void wkan_fused(const float* __restrict__ x,
                const float* __restrict__ basew,
                const float* __restrict__ wavew,
                const float* __restrict__ scale,
                const float* __restrict__ transl,
                const float* __restrict__ bias,
                float* __restrict__ out)
{
  // per-b arrays (rows = local b), per-o arrays (rows = local o)
  __shared__ float lx [BT * PITCH];
  __shared__ float lsx[BT * PITCH];
  __shared__ float la2[OT * PITCH];
  __shared__ float lm1[OT * PITCH];
  __shared__ float lm2[OT * PITCH];
  __shared__ float lw2[OT * PITCH];
  __shared__ float lw [OT * PITCH];
  __shared__ float lbb[OT * PITCH];

  const int tid = threadIdx.x;
  const int to  = tid & 15;   // o within tile (lanes 0..15 vary o -> coalesced store)
  const int tb  = tid >> 4;   // b within tile
  const int b0  = blockIdx.x * BT;
  const int o0  = blockIdx.y * OT;

  float aW00 = 0.f, aW01 = 0.f, aW10 = 0.f, aW11 = 0.f;
  float aB00 = 0.f, aB01 = 0.f, aB10 = 0.f, aB11 = 0.f;

  for (int kc = 0; kc < IN_F / IT; ++kc) {
    __syncthreads();
    // ---- stage chunk [kc*IT, kc*IT+IT) ----
#pragma unroll
    for (int k = 0; k < 2; ++k) {
      const int f    = tid + k * 256;
      const int row  = f >> 4;        // 0..31
      const int c4   = (f & 15) * 4;  // 0..60
      const int gofs = kc * IT + c4;
      const int lofs = row * PITCH + c4;

      float4 xv = *(const float4*)(x + (size_t)(b0 + row) * IN_F + gofs);
      float4 sxv;
      sxv.x = xv.x * fast_rcp(1.f + fast_exp2(xv.x * -LOG2E));
      sxv.y = xv.y * fast_rcp(1.f + fast_exp2(xv.y * -LOG2E));
      sxv.z = xv.z * fast_rcp(1.f + fast_exp2(xv.z * -LOG2E));
      sxv.w = xv.w * fast_rcp(1.f + fast_exp2(xv.w * -LOG2E));
      *(float4*)(lx  + lofs) = xv;
      *(float4*)(lsx + lofs) = sxv;

      float4 sv = *(const float4*)(scale  + (size_t)(o0 + row) * IN_F + gofs);
      float4 tv = *(const float4*)(transl + (size_t)(o0 + row) * IN_F + gofs);
      float4 a2, m1, m2;
      a2.x = C2 * fast_rcp(sv.x * sv.x);
      a2.y = C2 * fast_rcp(sv.y * sv.y);
      a2.z = C2 * fast_rcp(sv.z * sv.z);
      a2.w = C2 * fast_rcp(sv.w * sv.w);
      m1.x = -2.f * a2.x * tv.x;  m2.x = a2.x * tv.x * tv.x;
      m1.y = -2.f * a2.y * tv.y;  m2.y = a2.y * tv.y * tv.y;
      m1.z = -2.f * a2.z * tv.z;  m2.z = a2.z * tv.z * tv.z;
      m1.w = -2.f * a2.w * tv.w;  m2.w = a2.w * tv.w * tv.w;
      *(float4*)(la2 + lofs) = a2;
      *(float4*)(lm1 + lofs) = m1;
      *(float4*)(lm2 + lofs) = m2;

      float4 wv = *(const float4*)(wavew + (size_t)(o0 + row) * IN_F + gofs);
      float4 w2;
      w2.x = wv.x * RC2; w2.y = wv.y * RC2; w2.z = wv.z * RC2; w2.w = wv.w * RC2;
      *(float4*)(lw2 + lofs) = w2;
      *(float4*)(lw  + lofs) = wv;

      float4 bv = *(const float4*)(basew + (size_t)(o0 + row) * IN_F + gofs);
      *(float4*)(lbb + lofs) = bv;
    }
    __syncthreads();

    // ---- compute: 2x2 outputs per thread, rows (tb, tb+16) x (to, to+16) ----
    const float* px0 = lx  + tb * PITCH;
    const float* px1 = lx  + (tb + 16) * PITCH;
    const float* ps0 = lsx + tb * PITCH;
    const float* ps1 = lsx + (tb + 16) * PITCH;
    const float* pa0 = la2 + to * PITCH;
    const float* pa1 = la2 + (to + 16) * PITCH;
    const float* pm0 = lm1 + to * PITCH;
    const float* pm1 = lm1 + (to + 16) * PITCH;
    const float* pn0 = lm2 + to * PITCH;
    const float* pn1 = lm2 + (to + 16) * PITCH;
    const float* pq0 = lw2 + to * PITCH;
    const float* pq1 = lw2 + (to + 16) * PITCH;
    const float* pw0 = lw  + to * PITCH;
    const float* pw1 = lw  + (to + 16) * PITCH;
    const float* pb0 = lbb + to * PITCH;
    const float* pb1 = lbb + (to + 16) * PITCH;

#pragma unroll 4
    for (int ii = 0; ii < IT; ii += 4) {
      float4 xv0 = *(const float4*)(px0 + ii);
      float4 xv1 = *(const float4*)(px1 + ii);
      float4 sv0 = *(const float4*)(ps0 + ii);
      float4 sv1 = *(const float4*)(ps1 + ii);
      float4 av0 = *(const float4*)(pa0 + ii);
      float4 av1 = *(const float4*)(pa1 + ii);
      float4 mv0 = *(const float4*)(pm0 + ii);
      float4 mv1 = *(const float4*)(pm1 + ii);
      float4 nv0 = *(const float4*)(pn0 + ii);
      float4 nv1 = *(const float4*)(pn1 + ii);
      float4 qv0 = *(const float4*)(pq0 + ii);
      float4 qv1 = *(const float4*)(pq1 + ii);
      float4 wv0 = *(const float4*)(pw0 + ii);
      float4 wv1 = *(const float4*)(pw1 + ii);
      float4 bv0 = *(const float4*)(pb0 + ii);
      float4 bv1 = *(const float4*)(pb1 + ii);

      const float* X0 = (const float*)&xv0; const float* X1 = (const float*)&xv1;
      const float* S0 = (const float*)&sv0; const float* S1 = (const float*)&sv1;
      const float* A0 = (const float*)&av0; const float* A1 = (const float*)&av1;
      const float* M0 = (const float*)&mv0; const float* M1 = (const float*)&mv1;
      const float* N0 = (const float*)&nv0; const float* N1 = (const float*)&nv1;
      const float* Q0 = (const float*)&qv0; const float* Q1 = (const float*)&qv1;
      const float* W0 = (const float*)&wv0; const float* W1 = (const float*)&wv1;
      const float* B0 = (const float*)&bv0; const float* B1 = (const float*)&bv1;

#pragma unroll
      for (int j = 0; j < 4; ++j) {
        // (r=0,s=0)
        {
          float u = fmaf(X0[j], fmaf(X0[j], A0[j], M0[j]), N0[j]);
          float e = fast_exp2(u);
          float g = fmaf(u, Q0[j], -W0[j]);
          aW00 = fmaf(g, e, aW00);
          aB00 = fmaf(S0[j], B0[j], aB00);
        }
        // (r=0,s=1)
        {
          float u = fmaf(X0[j], fmaf(X0[j], A1[j], M1[j]), N1[j]);
          float e = fast_exp2(u);
          float g = fmaf(u, Q1[j], -W1[j]);
          aW01 = fmaf(g, e, aW01);
          aB01 = fmaf(S0[j], B1[j], aB01);
        }
        // (r=1,s=0)
        {
          float u = fmaf(X1[j], fmaf(X1[j], A0[j], M0[j]), N0[j]);
          float e = fast_exp2(u);
          float g = fmaf(u, Q0[j], -W0[j]);
          aW10 = fmaf(g, e, aW10);
          aB10 = fmaf(S1[j], B0[j], aB10);
        }
        // (r=1,s=1)
        {
          float u = fmaf(X1[j], fmaf(X1[j], A1[j], M1[j]), N1[j]);
          float e = fast_exp2(u);
          float g = fmaf(u, Q1[j], -W1[j]);
          aW11 = fmaf(g, e, aW11);
          aB11 = fmaf(S1[j], B1[j], aB11);
        }
      }
    }
  }

  const float bia0 = bias[o0 + to];
  const float bia1 = bias[o0 + to + 16];
  float* orow0 = out + (size_t)(b0 + tb) * OUT_F + o0;
  float* orow1 = out + (size_t)(b0 + tb + 16) * OUT_F + o0;
  orow0[to]      = aW00 + aB00 + bia0;
  orow0[to + 16] = aW01 + aB01 + bia1;
  orow1[to]      = aW10 + aB10 + bia0;
  orow1[to + 16] = aW11 + aB11 + bia1;
}

extern "C" void kernel_launch(void* const* d_in, const int* in_sizes, int n_in,
                              void* d_out, int out_size, void* d_ws, size_t ws_size,
                              hipStream_t stream) {
  const float* x   = (const float*)d_in[0];
  const float* bw  = (const float*)d_in[1];
  const float* ww  = (const float*)d_in[2];
  const float* sc  = (const float*)d_in[3];
  const float* tr  = (const float*)d_in[4];
  const float* bi  = (const float*)d_in[5];
  float* out = (float*)d_out;

  dim3 grid(BATCH / BT, OUT_F / OT);  // 32 x 16 = 512 blocks, 2/CU
  wkan_fused<<<grid, dim3(256), 0, stream>>>(x, bw, ww, sc, tr, bi, out);
}

// Round 2
// 117.647 us; speedup vs baseline: 1.1596x; 1.1596x over previous
//
#include <hip/hip_runtime.h>

// out[b,o] = sum_i silu(x)*BW + ((xs^2-1)*exp(-xs^2/2))*WW + bias
//   xs = (x-T)/S.  Per-(o,i) precompute (staging):
//     a2 = C2/s^2, m1 = -2*a2*t, m2' = a2*t^2 - C2, q = w * 2^C2 / C2
//   with C2 = -0.5*log2(e).  Then per (b,o,i):
//     p = a2*x^2 + m1*x + m2'          (= C2*xs^2 - C2)
//     contribution = p * q * 2^p       (identity: (xs^2-1)*w*e^{-xs^2/2})
//   inner = 2 fma + 1 mul + 1 exp2 + 2 fma-acc (base branch folded in),
//   written as packed-fp32 (v_pk_*) over k-pairs.

constexpr int IN_F  = 512;
constexpr int OUT_F = 512;
constexpr int BATCH = 1024;
constexpr int BT = 64, OT = 64;     // block tile
constexpr int KS = 4;               // k-split
constexpr int KR = IN_F / KS;       // 128 k per block
constexpr int IT = 16;              // k chunk in LDS
constexpr int PITCH = IT + 4;       // 20 floats: 16B-aligned rows, 2-way banks max
constexpr int NCH = KR / IT;        // 8 chunks
constexpr int BO  = BATCH * OUT_F;  // 524288

#define LOG2E 1.44269504088897f
#define C2f   (-0.72134752044448f)
#define NC2f  ( 0.72134752044448f)
#define RQf   (-0.84083003f)   /* 2^C2 / C2 = e^{-1/2}/C2 */

typedef float v2f __attribute__((ext_vector_type(2)));

__device__ __forceinline__ float fexp2(float v) { return __builtin_amdgcn_exp2f(v); }
__device__ __forceinline__ float frcp(float v)  { return __builtin_amdgcn_rcpf(v); }
__device__ __forceinline__ v2f pkfma(v2f a, v2f b, v2f c) {
#if __has_builtin(__builtin_elementwise_fma)
  return __builtin_elementwise_fma(a, b, c);
#else
  v2f r; r.x = fmaf(a.x, b.x, c.x); r.y = fmaf(a.y, b.y, c.y); return r;
#endif
}
__device__ __forceinline__ float fsilu(float v) {
  return v * frcp(1.f + fexp2(v * -LOG2E));
}

__global__ __launch_bounds__(256, 4)  // 4 blocks/CU (LDS 35.8KB), VGPR<=128
void wkan_main(const float* __restrict__ x, const float* __restrict__ basew,
               const float* __restrict__ wavew, const float* __restrict__ scale,
               const float* __restrict__ transl, const float* __restrict__ bias,
               float* __restrict__ partial, float* __restrict__ out, int use_ws)
{
  __shared__ float lx [BT * PITCH];
  __shared__ float lsx[BT * PITCH];
  __shared__ float la [OT * PITCH];
  __shared__ float lm [OT * PITCH];
  __shared__ float ln [OT * PITCH];
  __shared__ float lq [OT * PITCH];
  __shared__ float lb [OT * PITCH];

  const int tid = threadIdx.x;
  const int b0 = blockIdx.x * BT;
  const int o0 = blockIdx.y * OT;
  const int ks = blockIdx.z;
  const int k0 = ks * KR;

  const int srow = tid >> 2;        // 0..63 staging row
  const int sc4  = (tid & 3) * 4;   // 0..12 staging col (float4)
  const int lofs = srow * PITCH + sc4;

  const int to = tid & 15;          // output col group
  const int tb = tid >> 4;          // output row group

  v2f zz; zz.x = 0.f; zz.y = 0.f;
  v2f acc[4][4];
#pragma unroll
  for (int r = 0; r < 4; ++r)
#pragma unroll
    for (int c = 0; c < 4; ++c) acc[r][c] = zz;

  for (int kc = 0; kc < NCH; ++kc) {
    const int g = k0 + kc * IT + sc4;
    __syncthreads();
    // ---------- stage chunk ----------
    {
      float4 xv = *(const float4*)(x + (size_t)(b0 + srow) * IN_F + g);
      float4 sx;
      sx.x = fsilu(xv.x); sx.y = fsilu(xv.y); sx.z = fsilu(xv.z); sx.w = fsilu(xv.w);
      *(float4*)(lx  + lofs) = xv;
      *(float4*)(lsx + lofs) = sx;

      float4 sv = *(const float4*)(scale  + (size_t)(o0 + srow) * IN_F + g);
      float4 tv = *(const float4*)(transl + (size_t)(o0 + srow) * IN_F + g);
      float4 av, mv, nv;
      {
        float a2, a2t;
        a2 = C2f * frcp(sv.x * sv.x); a2t = a2 * tv.x;
        av.x = a2; mv.x = -2.f * a2t; nv.x = fmaf(a2t, tv.x, NC2f);
        a2 = C2f * frcp(sv.y * sv.y); a2t = a2 * tv.y;
        av.y = a2; mv.y = -2.f * a2t; nv.y = fmaf(a2t, tv.y, NC2f);
        a2 = C2f * frcp(sv.z * sv.z); a2t = a2 * tv.z;
        av.z = a2; mv.z = -2.f * a2t; nv.z = fmaf(a2t, tv.z, NC2f);
        a2 = C2f * frcp(sv.w * sv.w); a2t = a2 * tv.w;
        av.w = a2; mv.w = -2.f * a2t; nv.w = fmaf(a2t, tv.w, NC2f);
      }
      *(float4*)(la + lofs) = av;
      *(float4*)(lm + lofs) = mv;
      *(float4*)(ln + lofs) = nv;

      float4 wv = *(const float4*)(wavew + (size_t)(o0 + srow) * IN_F + g);
      float4 qv;
      qv.x = wv.x * RQf; qv.y = wv.y * RQf; qv.z = wv.z * RQf; qv.w = wv.w * RQf;
      *(float4*)(lq + lofs) = qv;

      float4 bv = *(const float4*)(basew + (size_t)(o0 + srow) * IN_F + g);
      *(float4*)(lb + lofs) = bv;
    }
    __syncthreads();

    // ---------- compute: 4x4 outputs/thread ----------
    for (int ii = 0; ii < IT; ii += 4) {
      float4 xr[4], sr[4], x2[4];
#pragma unroll
      for (int r = 0; r < 4; ++r) {
        const int row = (tb + 16 * r) * PITCH + ii;
        xr[r] = *(const float4*)(lx + row);
        sr[r] = *(const float4*)(lsx + row);
        x2[r].x = xr[r].x * xr[r].x;
        x2[r].y = xr[r].y * xr[r].y;
        x2[r].z = xr[r].z * xr[r].z;
        x2[r].w = xr[r].w * xr[r].w;
      }
#pragma unroll
      for (int c = 0; c < 4; ++c) {
        const int orow = (to + 16 * c) * PITCH + ii;
        float4 A = *(const float4*)(la + orow);
        float4 M = *(const float4*)(lm + orow);
        float4 N = *(const float4*)(ln + orow);
        float4 Q = *(const float4*)(lq + orow);
        float4 B = *(const float4*)(lb + orow);
        v2f Al = {A.x, A.y}, Ah = {A.z, A.w};
        v2f Ml = {M.x, M.y}, Mh = {M.z, M.w};
        v2f Nl = {N.x, N.y}, Nh = {N.z, N.w};
        v2f Ql = {Q.x, Q.y}, Qh = {Q.z, Q.w};
        v2f Bl = {B.x, B.y}, Bh = {B.z, B.w};
#pragma unroll
        for (int r = 0; r < 4; ++r) {
          v2f xl  = {xr[r].x, xr[r].y}, xh  = {xr[r].z, xr[r].w};
          v2f x2l = {x2[r].x, x2[r].y}, x2h = {x2[r].z, x2[r].w};
          v2f sl  = {sr[r].x, sr[r].y}, sh  = {sr[r].z, sr[r].w};
          v2f p, e, gg;
          p = pkfma(Al, x2l, pkfma(Ml, xl, Nl));
          e.x = fexp2(p.x); e.y = fexp2(p.y);
          gg = p * Ql;
          acc[r][c] = pkfma(gg, e, acc[r][c]);
          acc[r][c] = pkfma(sl, Bl, acc[r][c]);
          p = pkfma(Ah, x2h, pkfma(Mh, xh, Nh));
          e.x = fexp2(p.x); e.y = fexp2(p.y);
          gg = p * Qh;
          acc[r][c] = pkfma(gg, e, acc[r][c]);
          acc[r][c] = pkfma(sh, Bh, acc[r][c]);
        }
      }
    }
  }

  // ---------- epilogue ----------
#pragma unroll
  for (int r = 0; r < 4; ++r) {
    const int br = b0 + tb + 16 * r;
#pragma unroll
    for (int c = 0; c < 4; ++c) {
      const int oc = o0 + to + 16 * c;
      float res = acc[r][c].x + acc[r][c].y;
      if (use_ws) {
        partial[(size_t)ks * BO + (size_t)br * OUT_F + oc] = res;
      } else {
        if (ks == 0) res += bias[oc];
        atomicAdd(out + (size_t)br * OUT_F + oc, res);
      }
    }
  }
}

__global__ __launch_bounds__(256)
void wkan_reduce(const float* __restrict__ partial, const float* __restrict__ bias,
                 float* __restrict__ out)
{
  const int i4 = (blockIdx.x * 256 + threadIdx.x) * 4;
  float4 a = *(const float4*)(partial + i4);
  float4 b = *(const float4*)(partial + (size_t)BO + i4);
  float4 c = *(const float4*)(partial + (size_t)2 * BO + i4);
  float4 d = *(const float4*)(partial + (size_t)3 * BO + i4);
  float4 bi = *(const float4*)(bias + (i4 & (OUT_F - 1)));
  float4 r;
  r.x = a.x + b.x + c.x + d.x + bi.x;
  r.y = a.y + b.y + c.y + d.y + bi.y;
  r.z = a.z + b.z + c.z + d.z + bi.z;
  r.w = a.w + b.w + c.w + d.w + bi.w;
  *(float4*)(out + i4) = r;
}

extern "C" void kernel_launch(void* const* d_in, const int* in_sizes, int n_in,
                              void* d_out, int out_size, void* d_ws, size_t ws_size,
                              hipStream_t stream) {
  const float* x  = (const float*)d_in[0];
  const float* bw = (const float*)d_in[1];
  const float* ww = (const float*)d_in[2];
  const float* sc = (const float*)d_in[3];
  const float* tr = (const float*)d_in[4];
  const float* bi = (const float*)d_in[5];
  float* out = (float*)d_out;

  const int use_ws = ws_size >= (size_t)KS * BO * sizeof(float) ? 1 : 0;
  if (!use_ws) {
    hipMemsetAsync(d_out, 0, (size_t)out_size * sizeof(float), stream);
  }
  dim3 grid(BATCH / BT, OUT_F / OT, KS);  // 16 x 8 x 4 = 512 blocks, 2 resident/CU... 4 via LDS
  wkan_main<<<grid, dim3(256), 0, stream>>>(x, bw, ww, sc, tr, bi,
                                            (float*)d_ws, out, use_ws);
  if (use_ws) {
    wkan_reduce<<<dim3(BO / 1024), dim3(256), 0, stream>>>((const float*)d_ws, bi, out);
  }
}